// Round 7
// baseline (594.565 us; speedup 1.0000x reference)
//
#include <hip/hip_runtime.h>
#include <cstdint>
#include <cstddef>

typedef __attribute__((ext_vector_type(8))) short bf16x8;   // 8 bf16 in 4 VGPRs
typedef __attribute__((ext_vector_type(4))) float f32x4;

__device__ __forceinline__ unsigned short f2bf(float f) {
  union { float f; unsigned u; } v; v.f = f;
  unsigned r = v.u + 0x7FFFu + ((v.u >> 16) & 1u);   // round-to-nearest-even
  return (unsigned short)(r >> 16);
}

#define GLL(gp, lp) __builtin_amdgcn_global_load_lds( \
    (const __attribute__((address_space(1))) void*)(gp), \
    (__attribute__((address_space(3))) void*)(lp), 16, 0, 0)

#define BARRIER() do { \
  __builtin_amdgcn_sched_barrier(0); \
  __builtin_amdgcn_s_barrier(); \
  __builtin_amdgcn_sched_barrier(0); } while (0)

#define WAIT_LGKM0() do { \
  asm volatile("s_waitcnt lgkmcnt(0)"); \
  __builtin_amdgcn_sched_barrier(0); } while (0)

#define WAIT_VM0() do { \
  asm volatile("s_waitcnt vmcnt(0)"); \
  __builtin_amdgcn_sched_barrier(0); } while (0)

// ---------------- elementwise fp32 -> bf16 ----------------
__global__ void cvt_x_kernel(const float* __restrict__ x, unsigned short* __restrict__ xb, int n4) {
  int i = blockIdx.x * blockDim.x + threadIdx.x;
  if (i >= n4) return;
  const float4 v = reinterpret_cast<const float4*>(x)[i];
  ushort4 o;
  o.x = f2bf(v.x); o.y = f2bf(v.y); o.z = f2bf(v.z); o.w = f2bf(v.w);
  reinterpret_cast<ushort4*>(xb)[i] = o;
}

// ---------------- transpose fp32 (K x N) -> bf16 (N x K) ----------------
__global__ void transpose_kernel(const float* __restrict__ src, unsigned short* __restrict__ dst,
                                 int K, int N) {
  __shared__ float t[32][33];
  const int tx = threadIdx.x, ty = threadIdx.y;
  const int n0 = blockIdx.x * 32, k0 = blockIdx.y * 32;
#pragma unroll
  for (int i = 0; i < 4; ++i)
    t[ty + i * 8][tx] = src[(size_t)(k0 + ty + i * 8) * N + n0 + tx];
  __syncthreads();
#pragma unroll
  for (int i = 0; i < 4; ++i)
    dst[(size_t)(n0 + ty + i * 8) * K + k0 + tx] = f2bf(t[tx][ty + i * 8]);
}

// ---------------- 128x128 2-phase bf16 MFMA GEMM ----------------
// A: M x K row-major bf16. B: N x K row-major bf16 (weights pre-transposed).
// 256 threads = 4 waves (2x2); per-wave 64x64 C; BK=32; LDS 32 KB dbuf ->
// ~4 blocks/CU so barrier drains are hidden by co-resident blocks (m97 regime).
// Per tile: STAGE(t+1) issued FIRST (flies under reads+MFMA), then 8x
// ds_read_b128, lgkmcnt(0), 16 MFMA, vmcnt(0), barrier.
// LDS swizzle: row = 64B = 4 chunks of 16B; chunk c stored at slot c^((row>>1)&3)
// (applied BOTH sides: pre-swizzled global source + swizzled ds_read; GLL dest
// stays linear). Quarter-wave bank load = 2/bank (free, m136).

template <int EPI>
__global__ void gemm2p_kernel(
    const unsigned short* __restrict__ Ag, const unsigned short* __restrict__ Bg,
    int K, int N, int mtMask, int mtShift,
    float* __restrict__ yout,
    const float* __restrict__ fcos, const float* __restrict__ fsin,
    unsigned short* __restrict__ q_ws, unsigned short* __restrict__ k_ws,
    unsigned short* __restrict__ vT_ws,
    float* __restrict__ k_out, float* __restrict__ v_out) {
  __shared__ unsigned short Asb[2][128 * 32];   // [buf][row][32 elems]
  __shared__ unsigned short Bsb[2][128 * 32];

  const int tid = threadIdx.x;
  const int w = tid >> 6, lane = tid & 63;
  const int wr = w >> 1, wc = w & 1;             // 2x2 wave grid, 64x64 per wave
  const int g = lane >> 4, q16 = lane & 15;

  // T1: bijective XCD swizzle (grid % 8 == 0 by construction)
  const int cpx = (int)gridDim.x >> 3;
  int bid = (int)blockIdx.x;
  bid = (bid & 7) * cpx + (bid >> 3);
  const int bm = bid & mtMask, bn = bid >> mtShift;
  const int m0 = bm << 7, n0 = bn << 7;
  const int NT = K >> 5;

  // stage lane decomposition: per GLL a wave covers 16 rows x 4 slots
  const int srow = lane >> 2;                    // 0..15
  const int sslot = lane & 3;

  auto stageA = [&](int tile) {
    if (tile >= NT) return;
    unsigned short* dst = &Asb[tile & 1][0];
#pragma unroll
    for (int j = 0; j < 2; ++j) {
      const int row = w * 32 + j * 16 + srow;
      const int c = sslot ^ ((row >> 1) & 3);    // inverse swizzle on SOURCE
      GLL(Ag + (size_t)(m0 + row) * K + tile * 32 + c * 8,
          dst + (w * 32 + j * 16) * 32);
    }
  };
  auto stageB = [&](int tile) {
    if (tile >= NT) return;
    unsigned short* dst = &Bsb[tile & 1][0];
#pragma unroll
    for (int j = 0; j < 2; ++j) {
      const int row = w * 32 + j * 16 + srow;
      const int c = sslot ^ ((row >> 1) & 3);
      GLL(Bg + (size_t)(n0 + row) * K + tile * 32 + c * 8,
          dst + (w * 32 + j * 16) * 32);
    }
  };

  f32x4 acc[4][4] = {};

  stageA(0); stageB(0);
  WAIT_VM0();
  BARRIER();

  for (int t = 0; t < NT; ++t) {
    stageA(t + 1); stageB(t + 1);                // into buf^1, flies under compute
    const unsigned short* Ab = Asb[t & 1];
    const unsigned short* Bb = Bsb[t & 1];
    bf16x8 af[4], bfr[4];
#pragma unroll
    for (int i = 0; i < 4; ++i) {
      const int row = wr * 64 + i * 16 + q16;
      af[i] = *(const bf16x8*)(Ab + row * 32 + ((g ^ ((row >> 1) & 3)) << 3));
    }
#pragma unroll
    for (int j = 0; j < 4; ++j) {
      const int row = wc * 64 + j * 16 + q16;
      bfr[j] = *(const bf16x8*)(Bb + row * 32 + ((g ^ ((row >> 1) & 3)) << 3));
    }
    WAIT_LGKM0();                                 // rule #18
#pragma unroll
    for (int i = 0; i < 4; ++i)
#pragma unroll
      for (int j = 0; j < 4; ++j)
        acc[i][j] = __builtin_amdgcn_mfma_f32_16x16x32_bf16(af[i], bfr[j], acc[i][j], 0, 0, 0);
    WAIT_VM0();                                   // t+1 staged & landed
    BARRIER();
  }

  // ---- epilogue ----  C/D: col = q16, row = g*4 + r  (R2-verified)
#pragma unroll
  for (int i = 0; i < 4; ++i) {
#pragma unroll
    for (int j = 0; j < 4; ++j) {
#pragma unroll
      for (int r = 0; r < 4; ++r) {
        const int m = m0 + wr * 64 + i * 16 + g * 4 + r;
        const int n = n0 + wc * 64 + j * 16 + q16;
        const float val = acc[i][j][r];
        if (EPI == 0) {
          yout[(size_t)m * N + n] = val;
        } else {
          const int region = bn >> 4;            // 0=q, 1=k, 2=v
          const int h = bn & 15;
          const int b = m >> 11, tt = m & 2047;
          const int dcol = n & 127;
          const size_t idx = ((size_t)((b * 16 + h) * 2048 + tt)) * 128 + dcol;
          if (region == 2) {
            v_out[idx] = val;
            vT_ws[((size_t)(b * 16 + h) * 128 + dcol) * 2048 + tt] = f2bf(val);
          } else {
            const int fi = dcol >> 1;
            const float c = fcos[tt * 64 + fi];
            const float s = fsin[tt * 64 + fi];
            const float part = __shfl_xor(val, 1);
            const float ro = (dcol & 1) ? (part * s + val * c) : (val * c - part * s);
            if (region == 0) {
              q_ws[idx] = f2bf(ro * 0.08838834764831845f);   // fold 1/sqrt(hd)
            } else {
              k_out[idx] = ro;
              k_ws[idx] = f2bf(ro);
            }
          }
        }
      }
    }
  }
}

// ---------------- flash attention (unchanged, R2-verified) ----------------
__global__ __launch_bounds__(256, 2) void attn_kernel(
    const unsigned short* __restrict__ q_ws,
    const unsigned short* __restrict__ k_ws,
    const unsigned short* __restrict__ vT_ws,
    unsigned short* __restrict__ attnout) {
  __shared__ unsigned short Kl[2][64 * 128];    // [key][d], chunk16 ^= (key&7)
  __shared__ unsigned short Vl[2][128 * 64];    // [d][key], chunk16 ^= (d&7)
  __shared__ unsigned short Pl[4][2][16 * 64];  // per-wave per-qsub, byte ^= (q&7)<<4

  const int tid = threadIdx.x;
  const int w = tid >> 6, lane = tid & 63;
  const int g = lane >> 4, q16 = lane & 15;
  const int bh = blockIdx.x;
  const int qt = 15 - (int)blockIdx.y;          // heaviest q-tiles first
  const int b = bh >> 4, h = bh & 15;
  const int qbase = qt * 128;
  const int qb = qbase + w * 32;
  const size_t kvbase = (size_t)bh * 2048 * 128;

  const int krow_l = lane >> 4, kchunk = lane & 15;
  const int vrow_l = lane >> 3, vchunk = lane & 7;

  bf16x8 qf[2][4];
#pragma unroll
  for (int qs = 0; qs < 2; ++qs)
#pragma unroll
    for (int c = 0; c < 4; ++c)
      qf[qs][c] = *(const bf16x8*)&q_ws[kvbase + (size_t)(qb + qs * 16 + q16) * 128 + c * 32 + g * 8];

  f32x4 acc[2][8] = {};
  float mrun[2] = {-1e30f, -1e30f};
  float lrun[2] = {0.f, 0.f};

  const int nt = (qt + 1) * 2;

  auto stageK = [&](int buf, int kt) {
#pragma unroll
    for (int i = 0; i < 4; ++i) {
      const int slab = w * 4 + i;
      const int krow = slab * 4 + krow_l;
      GLL(k_ws + kvbase + (size_t)(kt + krow) * 128 + ((kchunk ^ (krow & 7)) << 3),
          ((unsigned short*)Kl[buf]) + slab * 512);
    }
  };
  auto stageV = [&](int buf, int kt) {
#pragma unroll
    for (int i = 0; i < 4; ++i) {
      const int slab = w * 4 + i;
      const int d = slab * 8 + vrow_l;
      GLL(vT_ws + kvbase + (size_t)d * 2048 + kt + ((vchunk ^ (d & 7)) << 3),
          ((unsigned short*)Vl[buf]) + slab * 512);
    }
  };

  stageK(0, 0); stageV(0, 0);
  int cur = 0;
  for (int it = 0; it < nt; ++it) {
    const int kt = it * 64;
    __syncthreads();
    if (it + 1 < nt) { stageK(cur ^ 1, kt + 64); stageV(cur ^ 1, kt + 64); }

    if (kt <= qb + 31) {
      f32x4 s[2][4];
#pragma unroll
      for (int qs = 0; qs < 2; ++qs)
#pragma unroll
        for (int t = 0; t < 4; ++t) s[qs][t] = f32x4{0.f, 0.f, 0.f, 0.f};
#pragma unroll
      for (int t = 0; t < 4; ++t) {
        const int key = t * 16 + q16;
#pragma unroll
        for (int c = 0; c < 4; ++c) {
          bf16x8 kf = *(const bf16x8*)&Kl[cur][key * 128 + (((c * 4 + g) ^ (key & 7)) << 3)];
          s[0][t] = __builtin_amdgcn_mfma_f32_16x16x32_bf16(kf, qf[0][c], s[0][t], 0, 0, 0);
          s[1][t] = __builtin_amdgcn_mfma_f32_16x16x32_bf16(kf, qf[1][c], s[1][t], 0, 0, 0);
        }
      }

#pragma unroll
      for (int qs = 0; qs < 2; ++qs) {
        const int qrow = qb + qs * 16 + q16;
        if (kt + 64 > qb + qs * 16) {
#pragma unroll
          for (int t = 0; t < 4; ++t)
#pragma unroll
            for (int r = 0; r < 4; ++r)
              if (kt + t * 16 + g * 4 + r > qrow) s[qs][t][r] = -1e30f;
        }
        float tm = s[qs][0][0];
#pragma unroll
        for (int t = 0; t < 4; ++t)
#pragma unroll
          for (int r = 0; r < 4; ++r) tm = fmaxf(tm, s[qs][t][r]);
        tm = fmaxf(tm, __shfl_xor(tm, 16));
        tm = fmaxf(tm, __shfl_xor(tm, 32));
        if (__any(tm > mrun[qs] + 8.0f)) {             // T13 defer-max
          const float mnew = fmaxf(mrun[qs], tm);
          const float fac = __expf(mrun[qs] - mnew);
          lrun[qs] *= fac;
          mrun[qs] = mnew;
          float fr0 = __shfl(fac, g * 4 + 0), fr1 = __shfl(fac, g * 4 + 1);
          float fr2 = __shfl(fac, g * 4 + 2), fr3 = __shfl(fac, g * 4 + 3);
#pragma unroll
          for (int n = 0; n < 8; ++n) {
            acc[qs][n][0] *= fr0; acc[qs][n][1] *= fr1;
            acc[qs][n][2] *= fr2; acc[qs][n][3] *= fr3;
          }
        }
        float ps = 0.f;
        unsigned pk[8];
#pragma unroll
        for (int t = 0; t < 4; ++t) {
          const float p0 = __expf(s[qs][t][0] - mrun[qs]);
          const float p1 = __expf(s[qs][t][1] - mrun[qs]);
          const float p2 = __expf(s[qs][t][2] - mrun[qs]);
          const float p3 = __expf(s[qs][t][3] - mrun[qs]);
          ps += (p0 + p1) + (p2 + p3);
          pk[t * 2]     = (unsigned)f2bf(p0) | ((unsigned)f2bf(p1) << 16);
          pk[t * 2 + 1] = (unsigned)f2bf(p2) | ((unsigned)f2bf(p3) << 16);
        }
        ps += __shfl_xor(ps, 16);
        ps += __shfl_xor(ps, 32);
        lrun[qs] += ps;
#pragma unroll
        for (int t = 0; t < 4; ++t) {
          const unsigned byteoff = (unsigned)(q16 * 128) +
              (((unsigned)(t * 32 + g * 8)) ^ ((unsigned)(q16 & 7) << 4));
          *(uint2*)((char*)&Pl[w][qs][0] + byteoff) = make_uint2(pk[t * 2], pk[t * 2 + 1]);
        }
      }

      asm volatile("s_waitcnt lgkmcnt(0)" ::: "memory");
      __builtin_amdgcn_sched_barrier(0);
#pragma unroll
      for (int ks = 0; ks < 2; ++ks) {
        const unsigned pcol = ((unsigned)(ks * 64 + g * 16)) ^ ((unsigned)(q16 & 7) << 4);
        bf16x8 pa0 = *(const bf16x8*)((char*)&Pl[w][0][0] + q16 * 128 + pcol);
        bf16x8 pa1 = *(const bf16x8*)((char*)&Pl[w][1][0] + q16 * 128 + pcol);
#pragma unroll
        for (int n = 0; n < 8; ++n) {
          const int d = n * 16 + q16;
          bf16x8 vf = *(const bf16x8*)&Vl[cur][d * 64 + (((ks * 4 + g) ^ (d & 7)) << 3)];
          acc[0][n] = __builtin_amdgcn_mfma_f32_16x16x32_bf16(pa0, vf, acc[0][n], 0, 0, 0);
          acc[1][n] = __builtin_amdgcn_mfma_f32_16x16x32_bf16(pa1, vf, acc[1][n], 0, 0, 0);
        }
      }
    }
    cur ^= 1;
  }

#pragma unroll
  for (int qs = 0; qs < 2; ++qs) {
    float rl[4];
#pragma unroll
    for (int r = 0; r < 4; ++r) rl[r] = 1.0f / __shfl(lrun[qs], g * 4 + r);
#pragma unroll
    for (int n = 0; n < 8; ++n) {
#pragma unroll
      for (int r = 0; r < 4; ++r) {
        const int q = qb + qs * 16 + g * 4 + r;
        const int d = n * 16 + q16;
        attnout[((size_t)(b * 2048 + q)) * 2048 + h * 128 + d] = f2bf(acc[qs][n][r] * rl[r]);
      }
    }
  }
}

extern "C" void kernel_launch(void* const* d_in, const int* in_sizes, int n_in,
                              void* d_out, int out_size, void* d_ws, size_t ws_size,
                              hipStream_t stream) {
  (void)in_sizes; (void)n_in; (void)out_size; (void)ws_size;
  const float* x    = (const float*)d_in[0];
  const float* fcos = (const float*)d_in[1];
  const float* fsin = (const float*)d_in[2];
  const float* Wqkv = (const float*)d_in[3];
  const float* Wout = (const float*)d_in[4];

  float* out   = (float*)d_out;
  float* y_out = out;
  float* k_out = out + (size_t)16777216;          // B*T*C
  float* v_out = out + (size_t)33554432;

  unsigned short* xb      = (unsigned short*)d_ws;     // 8192 x 2048
  unsigned short* wqkvT   = xb + 16777216;             // 6144 x 2048
  unsigned short* woutT   = wqkvT + 12582912;          // 2048 x 2048
  unsigned short* q_ws    = woutT + 4194304;           // (B,H,T,hd) pre-scaled
  unsigned short* k_ws    = q_ws + 16777216;           // (B,H,T,hd)
  unsigned short* vT_ws   = k_ws + 16777216;           // (B,H,hd,T)
  unsigned short* attnout = xb;                        // alias: x consumed by then

  cvt_x_kernel<<<16384, 256, 0, stream>>>(x, xb, 4194304);
  transpose_kernel<<<dim3(192, 64), dim3(32, 8), 0, stream>>>(Wqkv, wqkvT, 2048, 6144);
  transpose_kernel<<<dim3(64, 64), dim3(32, 8), 0, stream>>>(Wout, woutT, 2048, 2048);

  // GEMM1: 8192 x 6144 x 2048, fused RoPE/qkv epilogue. Grid 64x48 = 3072 (%8==0).
  gemm2p_kernel<1><<<3072, 256, 0, stream>>>(
      xb, wqkvT, 2048, 6144, 63, 6,
      nullptr, fcos, fsin, q_ws, k_ws, vT_ws, k_out, v_out);

  attn_kernel<<<dim3(64, 16), 256, 0, stream>>>(q_ws, k_ws, vT_ws, attnout);

  // GEMM2: 8192 x 2048 x 2048 -> y. Grid 64x16 = 1024 (%8==0).
  gemm2p_kernel<0><<<1024, 256, 0, stream>>>(
      attnout, woutT, 2048, 2048, 63, 6,
      y_out, nullptr, nullptr, nullptr, nullptr, nullptr, nullptr, nullptr);
}

// Round 8
// 560.112 us; speedup vs baseline: 1.0615x; 1.0615x over previous
//
#include <hip/hip_runtime.h>
#include <cstdint>
#include <cstddef>

typedef __attribute__((ext_vector_type(8))) short bf16x8;   // 8 bf16 in 4 VGPRs
typedef __attribute__((ext_vector_type(4))) float f32x4;

__device__ __forceinline__ unsigned short f2bf(float f) {
  union { float f; unsigned u; } v; v.f = f;
  unsigned r = v.u + 0x7FFFu + ((v.u >> 16) & 1u);   // round-to-nearest-even
  return (unsigned short)(r >> 16);
}

#define GLL(gp, lp) __builtin_amdgcn_global_load_lds( \
    (const __attribute__((address_space(1))) void*)(gp), \
    (__attribute__((address_space(3))) void*)(lp), 16, 0, 0)

#define BARRIER() do { \
  __builtin_amdgcn_sched_barrier(0); \
  __builtin_amdgcn_s_barrier(); \
  __builtin_amdgcn_sched_barrier(0); } while (0)

#define WAIT_LGKM0() do { \
  asm volatile("s_waitcnt lgkmcnt(0)"); \
  __builtin_amdgcn_sched_barrier(0); } while (0)

#define WAIT_VM(N) do { \
  asm volatile("s_waitcnt vmcnt(" #N ")"); \
  __builtin_amdgcn_sched_barrier(0); } while (0)

// ---------------- elementwise fp32 -> bf16 ----------------
__global__ void cvt_x_kernel(const float* __restrict__ x, unsigned short* __restrict__ xb, int n4) {
  int i = blockIdx.x * blockDim.x + threadIdx.x;
  if (i >= n4) return;
  const float4 v = reinterpret_cast<const float4*>(x)[i];
  ushort4 o;
  o.x = f2bf(v.x); o.y = f2bf(v.y); o.z = f2bf(v.z); o.w = f2bf(v.w);
  reinterpret_cast<ushort4*>(xb)[i] = o;
}

// ---------------- transpose fp32 (K x N) -> bf16 (N x K) ----------------
__global__ void transpose_kernel(const float* __restrict__ src, unsigned short* __restrict__ dst,
                                 int K, int N) {
  __shared__ float t[32][33];
  const int tx = threadIdx.x, ty = threadIdx.y;
  const int n0 = blockIdx.x * 32, k0 = blockIdx.y * 32;
#pragma unroll
  for (int i = 0; i < 4; ++i)
    t[ty + i * 8][tx] = src[(size_t)(k0 + ty + i * 8) * N + n0 + tx];
  __syncthreads();
#pragma unroll
  for (int i = 0; i < 4; ++i)
    dst[(size_t)(n0 + ty + i * 8) * K + k0 + tx] = f2bf(t[tx][ty + i * 8]);
}

// ---------------- 128x128 depth-2 pipelined bf16 MFMA GEMM ----------------
// A: M x K row-major bf16. B: N x K row-major bf16 (weights pre-transposed).
// 256 threads = 4 waves (2x2); per-wave 64x64 C; BK=32.
// 3 LDS buffers (48 KB) -> 3 blocks/CU. Depth-2 counted pipeline:
//   iter t: vmcnt(4) [retires stage(t), stage(t+1) stays in flight]; barrier;
//           issue stage(t+2); 8x ds_read_b128 tile t; lgkmcnt(0); 16 MFMA.
// Single barrier/iter is race-free: GLL(t+2) targets buf[(t-1)%3], whose
// ds_reads all precede barrier(t) in each wave's program order.
// Tile map: XCD x owns bm in [x*8, x*8+8) (A-slice 4MB = L2-resident),
// bm-fastest within slice, bn outer -> B columns L3-hot across XCDs.
// LDS swizzle (R7-verified): 16B chunk c of row r at slot c ^ ((r>>1)&3),
// pre-swizzled global source + linear GLL dest + swizzled ds_read.

template <int EPI>
__global__ void gemm2p_kernel(
    const unsigned short* __restrict__ Ag, const unsigned short* __restrict__ Bg,
    int K, int N,
    float* __restrict__ yout,
    const float* __restrict__ fcos, const float* __restrict__ fsin,
    unsigned short* __restrict__ q_ws, unsigned short* __restrict__ k_ws,
    unsigned short* __restrict__ vT_ws,
    float* __restrict__ k_out, float* __restrict__ v_out) {
  __shared__ unsigned short Asb[3][128 * 32];   // [buf][row][32 elems]
  __shared__ unsigned short Bsb[3][128 * 32];

  const int tid = threadIdx.x;
  const int w = tid >> 6, lane = tid & 63;
  const int wr = w >> 1, wc = w & 1;             // 2x2 wave grid, 64x64 per wave
  const int g = lane >> 4, q16 = lane & 15;

  // XCD-sliced tile map (M=8192 -> 64 m-tiles; 8 per XCD)
  const int xcd = (int)blockIdx.x & 7;
  const int i = (int)blockIdx.x >> 3;
  const int bm = xcd * 8 + (i & 7);
  const int bn = i >> 3;
  const int m0 = bm << 7, n0 = bn << 7;
  const int NT = K >> 5;

  // stage lane decomposition: per GLL a wave covers 16 rows x 4 slots
  const int srow = lane >> 2;                    // 0..15
  const int sslot = lane & 3;

  auto stageA = [&](int tile) {
    if (tile >= NT) return;
    unsigned short* dst = &Asb[tile % 3][0];
#pragma unroll
    for (int j = 0; j < 2; ++j) {
      const int row = w * 32 + j * 16 + srow;
      const int c = sslot ^ ((row >> 1) & 3);    // inverse swizzle on SOURCE
      GLL(Ag + (size_t)(m0 + row) * K + tile * 32 + c * 8,
          dst + (w * 32 + j * 16) * 32);
    }
  };
  auto stageB = [&](int tile) {
    if (tile >= NT) return;
    unsigned short* dst = &Bsb[tile % 3][0];
#pragma unroll
    for (int j = 0; j < 2; ++j) {
      const int row = w * 32 + j * 16 + srow;
      const int c = sslot ^ ((row >> 1) & 3);
      GLL(Bg + (size_t)(n0 + row) * K + tile * 32 + c * 8,
          dst + (w * 32 + j * 16) * 32);
    }
  };

  f32x4 acc[4][4] = {};

  // prologue: stage tiles 0 and 1 (8 GLLs outstanding)
  stageA(0); stageB(0);
  stageA(1); stageB(1);

  for (int t = 0; t < NT; ++t) {
    if (t < NT - 1) { WAIT_VM(4); }              // stage(t) landed; t+1 in flight
    else            { WAIT_VM(0); }
    BARRIER();                                    // all waves see tile t complete
    stageA(t + 2); stageB(t + 2);                 // into buf[(t+2)%3], flies under MFMA
    const unsigned short* Ab = Asb[t % 3];
    const unsigned short* Bb = Bsb[t % 3];
    bf16x8 af[4], bfr[4];
#pragma unroll
    for (int ii = 0; ii < 4; ++ii) {
      const int row = wr * 64 + ii * 16 + q16;
      af[ii] = *(const bf16x8*)(Ab + row * 32 + ((g ^ ((row >> 1) & 3)) << 3));
    }
#pragma unroll
    for (int j = 0; j < 4; ++j) {
      const int row = wc * 64 + j * 16 + q16;
      bfr[j] = *(const bf16x8*)(Bb + row * 32 + ((g ^ ((row >> 1) & 3)) << 3));
    }
    WAIT_LGKM0();                                 // rule #18
#pragma unroll
    for (int ii = 0; ii < 4; ++ii)
#pragma unroll
      for (int j = 0; j < 4; ++j)
        acc[ii][j] = __builtin_amdgcn_mfma_f32_16x16x32_bf16(af[ii], bfr[j], acc[ii][j], 0, 0, 0);
  }

  // ---- epilogue ----  C/D: col = q16, row = g*4 + r  (R2-verified)
#pragma unroll
  for (int ii = 0; ii < 4; ++ii) {
#pragma unroll
    for (int j = 0; j < 4; ++j) {
#pragma unroll
      for (int r = 0; r < 4; ++r) {
        const int m = m0 + wr * 64 + ii * 16 + g * 4 + r;
        const int n = n0 + wc * 64 + j * 16 + q16;
        const float val = acc[ii][j][r];
        if (EPI == 0) {
          yout[(size_t)m * N + n] = val;
        } else {
          const int region = bn >> 4;            // 0=q, 1=k, 2=v
          const int h = bn & 15;
          const int b = m >> 11, tt = m & 2047;
          const int dcol = n & 127;
          const size_t idx = ((size_t)((b * 16 + h) * 2048 + tt)) * 128 + dcol;
          if (region == 2) {
            v_out[idx] = val;
            vT_ws[((size_t)(b * 16 + h) * 128 + dcol) * 2048 + tt] = f2bf(val);
          } else {
            const int fi = dcol >> 1;
            const float c = fcos[tt * 64 + fi];
            const float s = fsin[tt * 64 + fi];
            const float part = __shfl_xor(val, 1);
            const float ro = (dcol & 1) ? (part * s + val * c) : (val * c - part * s);
            if (region == 0) {
              q_ws[idx] = f2bf(ro * 0.08838834764831845f);   // fold 1/sqrt(hd)
            } else {
              k_out[idx] = ro;
              k_ws[idx] = f2bf(ro);
            }
          }
        }
      }
    }
  }
}

// ---------------- flash attention (unchanged, R2-verified) ----------------
__global__ __launch_bounds__(256, 2) void attn_kernel(
    const unsigned short* __restrict__ q_ws,
    const unsigned short* __restrict__ k_ws,
    const unsigned short* __restrict__ vT_ws,
    unsigned short* __restrict__ attnout) {
  __shared__ unsigned short Kl[2][64 * 128];    // [key][d], chunk16 ^= (key&7)
  __shared__ unsigned short Vl[2][128 * 64];    // [d][key], chunk16 ^= (d&7)
  __shared__ unsigned short Pl[4][2][16 * 64];  // per-wave per-qsub, byte ^= (q&7)<<4

  const int tid = threadIdx.x;
  const int w = tid >> 6, lane = tid & 63;
  const int g = lane >> 4, q16 = lane & 15;
  const int bh = blockIdx.x;
  const int qt = 15 - (int)blockIdx.y;          // heaviest q-tiles first
  const int b = bh >> 4, h = bh & 15;
  const int qbase = qt * 128;
  const int qb = qbase + w * 32;
  const size_t kvbase = (size_t)bh * 2048 * 128;

  const int krow_l = lane >> 4, kchunk = lane & 15;
  const int vrow_l = lane >> 3, vchunk = lane & 7;

  bf16x8 qf[2][4];
#pragma unroll
  for (int qs = 0; qs < 2; ++qs)
#pragma unroll
    for (int c = 0; c < 4; ++c)
      qf[qs][c] = *(const bf16x8*)&q_ws[kvbase + (size_t)(qb + qs * 16 + q16) * 128 + c * 32 + g * 8];

  f32x4 acc[2][8] = {};
  float mrun[2] = {-1e30f, -1e30f};
  float lrun[2] = {0.f, 0.f};

  const int nt = (qt + 1) * 2;

  auto stageK = [&](int buf, int kt) {
#pragma unroll
    for (int i = 0; i < 4; ++i) {
      const int slab = w * 4 + i;
      const int krow = slab * 4 + krow_l;
      GLL(k_ws + kvbase + (size_t)(kt + krow) * 128 + ((kchunk ^ (krow & 7)) << 3),
          ((unsigned short*)Kl[buf]) + slab * 512);
    }
  };
  auto stageV = [&](int buf, int kt) {
#pragma unroll
    for (int i = 0; i < 4; ++i) {
      const int slab = w * 4 + i;
      const int d = slab * 8 + vrow_l;
      GLL(vT_ws + kvbase + (size_t)d * 2048 + kt + ((vchunk ^ (d & 7)) << 3),
          ((unsigned short*)Vl[buf]) + slab * 512);
    }
  };

  stageK(0, 0); stageV(0, 0);
  int cur = 0;
  for (int it = 0; it < nt; ++it) {
    const int kt = it * 64;
    __syncthreads();
    if (it + 1 < nt) { stageK(cur ^ 1, kt + 64); stageV(cur ^ 1, kt + 64); }

    if (kt <= qb + 31) {
      f32x4 s[2][4];
#pragma unroll
      for (int qs = 0; qs < 2; ++qs)
#pragma unroll
        for (int t = 0; t < 4; ++t) s[qs][t] = f32x4{0.f, 0.f, 0.f, 0.f};
#pragma unroll
      for (int t = 0; t < 4; ++t) {
        const int key = t * 16 + q16;
#pragma unroll
        for (int c = 0; c < 4; ++c) {
          bf16x8 kf = *(const bf16x8*)&Kl[cur][key * 128 + (((c * 4 + g) ^ (key & 7)) << 3)];
          s[0][t] = __builtin_amdgcn_mfma_f32_16x16x32_bf16(kf, qf[0][c], s[0][t], 0, 0, 0);
          s[1][t] = __builtin_amdgcn_mfma_f32_16x16x32_bf16(kf, qf[1][c], s[1][t], 0, 0, 0);
        }
      }

#pragma unroll
      for (int qs = 0; qs < 2; ++qs) {
        const int qrow = qb + qs * 16 + q16;
        if (kt + 64 > qb + qs * 16) {
#pragma unroll
          for (int t = 0; t < 4; ++t)
#pragma unroll
            for (int r = 0; r < 4; ++r)
              if (kt + t * 16 + g * 4 + r > qrow) s[qs][t][r] = -1e30f;
        }
        float tm = s[qs][0][0];
#pragma unroll
        for (int t = 0; t < 4; ++t)
#pragma unroll
          for (int r = 0; r < 4; ++r) tm = fmaxf(tm, s[qs][t][r]);
        tm = fmaxf(tm, __shfl_xor(tm, 16));
        tm = fmaxf(tm, __shfl_xor(tm, 32));
        if (__any(tm > mrun[qs] + 8.0f)) {             // T13 defer-max
          const float mnew = fmaxf(mrun[qs], tm);
          const float fac = __expf(mrun[qs] - mnew);
          lrun[qs] *= fac;
          mrun[qs] = mnew;
          float fr0 = __shfl(fac, g * 4 + 0), fr1 = __shfl(fac, g * 4 + 1);
          float fr2 = __shfl(fac, g * 4 + 2), fr3 = __shfl(fac, g * 4 + 3);
#pragma unroll
          for (int n = 0; n < 8; ++n) {
            acc[qs][n][0] *= fr0; acc[qs][n][1] *= fr1;
            acc[qs][n][2] *= fr2; acc[qs][n][3] *= fr3;
          }
        }
        float ps = 0.f;
        unsigned pk[8];
#pragma unroll
        for (int t = 0; t < 4; ++t) {
          const float p0 = __expf(s[qs][t][0] - mrun[qs]);
          const float p1 = __expf(s[qs][t][1] - mrun[qs]);
          const float p2 = __expf(s[qs][t][2] - mrun[qs]);
          const float p3 = __expf(s[qs][t][3] - mrun[qs]);
          ps += (p0 + p1) + (p2 + p3);
          pk[t * 2]     = (unsigned)f2bf(p0) | ((unsigned)f2bf(p1) << 16);
          pk[t * 2 + 1] = (unsigned)f2bf(p2) | ((unsigned)f2bf(p3) << 16);
        }
        ps += __shfl_xor(ps, 16);
        ps += __shfl_xor(ps, 32);
        lrun[qs] += ps;
#pragma unroll
        for (int t = 0; t < 4; ++t) {
          const unsigned byteoff = (unsigned)(q16 * 128) +
              (((unsigned)(t * 32 + g * 8)) ^ ((unsigned)(q16 & 7) << 4));
          *(uint2*)((char*)&Pl[w][qs][0] + byteoff) = make_uint2(pk[t * 2], pk[t * 2 + 1]);
        }
      }

      asm volatile("s_waitcnt lgkmcnt(0)" ::: "memory");
      __builtin_amdgcn_sched_barrier(0);
#pragma unroll
      for (int ks = 0; ks < 2; ++ks) {
        const unsigned pcol = ((unsigned)(ks * 64 + g * 16)) ^ ((unsigned)(q16 & 7) << 4);
        bf16x8 pa0 = *(const bf16x8*)((char*)&Pl[w][0][0] + q16 * 128 + pcol);
        bf16x8 pa1 = *(const bf16x8*)((char*)&Pl[w][1][0] + q16 * 128 + pcol);
#pragma unroll
        for (int n = 0; n < 8; ++n) {
          const int d = n * 16 + q16;
          bf16x8 vf = *(const bf16x8*)&Vl[cur][d * 64 + (((ks * 4 + g) ^ (d & 7)) << 3)];
          acc[0][n] = __builtin_amdgcn_mfma_f32_16x16x32_bf16(pa0, vf, acc[0][n], 0, 0, 0);
          acc[1][n] = __builtin_amdgcn_mfma_f32_16x16x32_bf16(pa1, vf, acc[1][n], 0, 0, 0);
        }
      }
    }
    cur ^= 1;
  }

#pragma unroll
  for (int qs = 0; qs < 2; ++qs) {
    float rl[4];
#pragma unroll
    for (int r = 0; r < 4; ++r) rl[r] = 1.0f / __shfl(lrun[qs], g * 4 + r);
#pragma unroll
    for (int n = 0; n < 8; ++n) {
#pragma unroll
      for (int r = 0; r < 4; ++r) {
        const int q = qb + qs * 16 + g * 4 + r;
        const int d = n * 16 + q16;
        attnout[((size_t)(b * 2048 + q)) * 2048 + h * 128 + d] = f2bf(acc[qs][n][r] * rl[r]);
      }
    }
  }
}

extern "C" void kernel_launch(void* const* d_in, const int* in_sizes, int n_in,
                              void* d_out, int out_size, void* d_ws, size_t ws_size,
                              hipStream_t stream) {
  (void)in_sizes; (void)n_in; (void)out_size; (void)ws_size;
  const float* x    = (const float*)d_in[0];
  const float* fcos = (const float*)d_in[1];
  const float* fsin = (const float*)d_in[2];
  const float* Wqkv = (const float*)d_in[3];
  const float* Wout = (const float*)d_in[4];

  float* out   = (float*)d_out;
  float* y_out = out;
  float* k_out = out + (size_t)16777216;          // B*T*C
  float* v_out = out + (size_t)33554432;

  unsigned short* xb      = (unsigned short*)d_ws;     // 8192 x 2048
  unsigned short* wqkvT   = xb + 16777216;             // 6144 x 2048
  unsigned short* woutT   = wqkvT + 12582912;          // 2048 x 2048
  unsigned short* q_ws    = woutT + 4194304;           // (B,H,T,hd) pre-scaled
  unsigned short* k_ws    = q_ws + 16777216;           // (B,H,T,hd)
  unsigned short* vT_ws   = k_ws + 16777216;           // (B,H,hd,T)
  unsigned short* attnout = xb;                        // alias: x consumed by then

  cvt_x_kernel<<<16384, 256, 0, stream>>>(x, xb, 4194304);
  transpose_kernel<<<dim3(192, 64), dim3(32, 8), 0, stream>>>(Wqkv, wqkvT, 2048, 6144);
  transpose_kernel<<<dim3(64, 64), dim3(32, 8), 0, stream>>>(Wout, woutT, 2048, 2048);

  // GEMM1: 8192 x 6144 x 2048, fused RoPE/qkv epilogue. Grid 3072.
  gemm2p_kernel<1><<<3072, 256, 0, stream>>>(
      xb, wqkvT, 2048, 6144,
      nullptr, fcos, fsin, q_ws, k_ws, vT_ws, k_out, v_out);

  attn_kernel<<<dim3(64, 16), 256, 0, stream>>>(q_ws, k_ws, vT_ws, attnout);

  // GEMM2: 8192 x 2048 x 2048 -> y. Grid 1024.
  gemm2p_kernel<0><<<1024, 256, 0, stream>>>(
      attnout, woutT, 2048, 2048,
      y_out, nullptr, nullptr, nullptr, nullptr, nullptr, nullptr, nullptr);
}